// Round 1
// baseline (1519.784 us; speedup 1.0000x reference)
//
#include <hip/hip_runtime.h>
#include <math.h>
#include <float.h>

// GNN layer pipeline, all fp32.
// Phase A: per-edge alpha + CSR build; segment_max by obj (atomic-free, wave/node)
// Phase B: hn1 = agg @ Wh  (stored in d_out as scratch)
// Phase C: edge scores + global online softmax (two-level)
// Phase D: t[s] = sum_e w_e * hn1[obj_e]; wsum[s] = sum_e w_e  (wave/node via CSR-sub)
// Phase E: out = t @ Wnode_w + wsum * Wnode_b   (overwrites d_out)

#define SCAN_BLK 256
#define SCAN_ITEMS 4
#define SCAN_CHUNK (SCAN_BLK * SCAN_ITEMS)
#define SOFT_G 2048

// ---------- K0: tiny tables: s2[rel][j] = rela[rel]@Wr ; s3[b][j] = rela[q_rel[b]]@Wqr_w + Wqr_b
__global__ void k_tables(const float* __restrict__ rela, const float* __restrict__ Wr,
                         const float* __restrict__ Wqr_w, const float* __restrict__ Wqr_b,
                         const int* __restrict__ q_rel,
                         float* __restrict__ s2, float* __restrict__ s3,
                         int nrel, int batch) {
  int tid = blockIdx.x * blockDim.x + threadIdx.x;
  int stride = gridDim.x * blockDim.x;
  for (int idx = tid; idx < nrel * 5; idx += stride) {
    int r = idx / 5, j = idx % 5;
    float acc = 0.f;
    for (int k = 0; k < 64; k++) acc += rela[r * 64 + k] * Wr[k * 5 + j];
    s2[idx] = acc;
  }
  for (int idx = tid; idx < batch * 5; idx += stride) {
    int b = idx / 5, j = idx % 5;
    int qr = q_rel[b];
    float acc = Wqr_b[j];
    for (int k = 0; k < 64; k++) acc += rela[qr * 64 + k] * Wqr_w[k * 5 + j];
    s3[idx] = acc;
  }
}

// ---------- K2: degree histogram (cnt[0..N)=by obj, cnt[N..2N)=by sub)
__global__ void k_hist(const int* __restrict__ edges, int* __restrict__ cnt, int E, int N) {
  int e = blockIdx.x * blockDim.x + threadIdx.x;
  if (e < E) {
    int sub = edges[e * 6 + 4];
    int obj = edges[e * 6 + 5];
    atomicAdd(&cnt[obj], 1);
    atomicAdd(&cnt[N + sub], 1);
  }
}

// ---------- K3a: per-block partial sums for scan
__global__ void k_scan_partial(const int* __restrict__ cnt, int* __restrict__ part, int n) {
  __shared__ int sdata[SCAN_BLK];
  int base = blockIdx.x * SCAN_CHUNK + threadIdx.x * SCAN_ITEMS;
  int s = 0;
#pragma unroll
  for (int j = 0; j < SCAN_ITEMS; j++) { int i = base + j; if (i < n) s += cnt[i]; }
  sdata[threadIdx.x] = s;
  __syncthreads();
  for (int d = SCAN_BLK / 2; d > 0; d >>= 1) {
    if (threadIdx.x < d) sdata[threadIdx.x] += sdata[threadIdx.x + d];
    __syncthreads();
  }
  if (threadIdx.x == 0) part[blockIdx.x] = sdata[0];
}

// ---------- K3b: exclusive scan of block sums (nblk <= 1024)
__global__ void k_scan_top(int* part, int nblk) {
  __shared__ int lds[1024];
  int tid = threadIdx.x;
  int v = (tid < nblk) ? part[tid] : 0;
  lds[tid] = v;
  __syncthreads();
  for (int d = 1; d < 1024; d <<= 1) {
    int t = (tid >= d) ? lds[tid - d] : 0;
    __syncthreads();
    lds[tid] += t;
    __syncthreads();
  }
  if (tid < nblk) part[tid] = lds[tid] - v;  // exclusive
}

// ---------- K3c: final exclusive scan -> off
__global__ void k_scan_final(const int* __restrict__ cnt, const int* __restrict__ part,
                             int* __restrict__ off, int n) {
  __shared__ int lds[SCAN_BLK];
  int tid = threadIdx.x;
  int base = blockIdx.x * SCAN_CHUNK + tid * SCAN_ITEMS;
  int c[SCAN_ITEMS];
  int s = 0;
#pragma unroll
  for (int j = 0; j < SCAN_ITEMS; j++) { int i = base + j; c[j] = (i < n) ? cnt[i] : 0; s += c[j]; }
  int v = s;
  lds[tid] = s;
  __syncthreads();
  for (int d = 1; d < SCAN_BLK; d <<= 1) {
    int t = (tid >= d) ? lds[tid - d] : 0;
    __syncthreads();
    lds[tid] += t;
    __syncthreads();
  }
  int run = part[blockIdx.x] + (lds[tid] - v);
#pragma unroll
  for (int j = 0; j < SCAN_ITEMS; j++) { int i = base + j; if (i < n) off[i] = run; run += c[j]; }
}

// ---------- K4: scatter edge ids into CSR lists + compute alpha per edge
__global__ void k_scatter_alpha(const int* __restrict__ edges,
                                const float* __restrict__ hidden,
                                const float* __restrict__ Ws_g,
                                const float* __restrict__ s2_g,
                                const float* __restrict__ s3_g,
                                const float* __restrict__ walpha_w,
                                const float* __restrict__ walpha_b,
                                int* __restrict__ cursor,
                                int* __restrict__ eid_obj, int* __restrict__ eid_sub,
                                float* __restrict__ alpha,
                                int E, int N, int nrel, int batch) {
  extern __shared__ float smem[];
  float* Ws_s = smem;                 // 320
  float* s2_s = Ws_s + 320;           // nrel*5
  float* s3_s = s2_s + nrel * 5;      // batch*5
  float* wa_s = s3_s + batch * 5;     // 6
  for (int i = threadIdx.x; i < 320; i += blockDim.x) Ws_s[i] = Ws_g[i];
  for (int i = threadIdx.x; i < nrel * 5; i += blockDim.x) s2_s[i] = s2_g[i];
  for (int i = threadIdx.x; i < batch * 5; i += blockDim.x) s3_s[i] = s3_g[i];
  if (threadIdx.x < 5) wa_s[threadIdx.x] = walpha_w[threadIdx.x];
  if (threadIdx.x == 5) wa_s[5] = walpha_b[0];
  __syncthreads();
  int e = blockIdx.x * blockDim.x + threadIdx.x;
  if (e >= E) return;
  int ridx = edges[e * 6 + 0];
  int rel  = edges[e * 6 + 2];
  int sub  = edges[e * 6 + 4];
  int obj  = edges[e * 6 + 5];
  int p1 = atomicAdd(&cursor[obj], 1);
  eid_obj[p1] = e;
  int p2 = atomicAdd(&cursor[N + sub], 1);
  eid_sub[p2 - E] = e;   // sub-part of the concatenated scan is offset by E

  float hs[64];
  const float4* hs4 = (const float4*)(hidden + (size_t)sub * 64);
#pragma unroll
  for (int k4 = 0; k4 < 16; k4++) {
    float4 h = hs4[k4];
    hs[k4 * 4 + 0] = h.x; hs[k4 * 4 + 1] = h.y; hs[k4 * 4 + 2] = h.z; hs[k4 * 4 + 3] = h.w;
  }
  float v[5];
#pragma unroll
  for (int j = 0; j < 5; j++) v[j] = s2_s[rel * 5 + j] + s3_s[ridx * 5 + j];
#pragma unroll 4
  for (int k = 0; k < 64; k++) {
    float h = hs[k];
#pragma unroll
    for (int j = 0; j < 5; j++) v[j] += h * Ws_s[k * 5 + j];
  }
  float z = wa_s[5];
#pragma unroll
  for (int j = 0; j < 5; j++) { float r = v[j] > 0.f ? v[j] : 0.f; z += r * wa_s[j]; }
  alpha[e] = 1.f / (1.f + expf(-z));
}

// ---------- K6: segment_max by obj -> agg (wave per node, lane = dim)
__global__ void k_agg(const int* __restrict__ edges, const int* __restrict__ off,
                      const int* __restrict__ eid_obj, const float* __restrict__ alpha,
                      const float* __restrict__ hidden, const float* __restrict__ rela,
                      float* __restrict__ agg, int N) {
  int lane = threadIdx.x & 63;
  int widx = threadIdx.x >> 6;
  int node = blockIdx.x * (blockDim.x >> 6) + widx;
  if (node >= N) return;
  int b = off[node], en = off[node + 1];  // off[N] == E (start of sub-part)
  float vmax = -FLT_MAX;
  for (int i = b; i < en; i++) {
    int eid = __builtin_amdgcn_readfirstlane(eid_obj[i]);
    int sub = __builtin_amdgcn_readfirstlane(edges[eid * 6 + 4]);
    int rel = __builtin_amdgcn_readfirstlane(edges[eid * 6 + 2]);
    float a = alpha[eid];
    float x = a * (hidden[(size_t)sub * 64 + lane] - rela[rel * 64 + lane]);
    vmax = fmaxf(vmax, x);
  }
  agg[(size_t)node * 64 + lane] = (en > b) ? vmax : 0.f;
}

// ---------- K7: C = A @ W (NxK @ KxD, K=D=64), thread per node, W in LDS
__global__ void k_mm(const float* __restrict__ A, const float* __restrict__ W,
                     float* __restrict__ C, int N) {
  __shared__ float Wls[4096];
  for (int i = threadIdx.x; i < 4096; i += blockDim.x) Wls[i] = W[i];
  __syncthreads();
  int n = blockIdx.x * blockDim.x + threadIdx.x;
  if (n >= N) return;
  float a[64];
  const float4* A4 = (const float4*)(A + (size_t)n * 64);
#pragma unroll
  for (int k4 = 0; k4 < 16; k4++) {
    float4 h = A4[k4];
    a[k4 * 4 + 0] = h.x; a[k4 * 4 + 1] = h.y; a[k4 * 4 + 2] = h.z; a[k4 * 4 + 3] = h.w;
  }
  float4* C4 = (float4*)(C + (size_t)n * 64);
#pragma unroll
  for (int c = 0; c < 4; c++) {
    float acc[16];
#pragma unroll
    for (int j = 0; j < 16; j++) acc[j] = 0.f;
    for (int k = 0; k < 64; k++) {
      float ak = a[k];
#pragma unroll
      for (int j = 0; j < 16; j++) acc[j] += ak * Wls[k * 64 + c * 16 + j];
    }
#pragma unroll
    for (int q = 0; q < 4; q++)
      C4[c * 4 + q] = make_float4(acc[q * 4], acc[q * 4 + 1], acc[q * 4 + 2], acc[q * 4 + 3]);
  }
}

// ---------- K8: scores + per-block online softmax partials
__global__ void k_scores(const int* __restrict__ edges, const float* __restrict__ hn,
                         const float* __restrict__ fw, const float* __restrict__ fb,
                         float* __restrict__ scores, float* __restrict__ pmax,
                         float* __restrict__ psum, int E) {
  __shared__ float fws[128];
  __shared__ float red_m[256], red_s[256];
  for (int i = threadIdx.x; i < 128; i += blockDim.x) fws[i] = fw[i];
  __syncthreads();
  float b = fb[0];
  float lm = -FLT_MAX, ls = 0.f;
  for (int e = blockIdx.x * blockDim.x + threadIdx.x; e < E; e += gridDim.x * blockDim.x) {
    int sub = edges[e * 6 + 4], obj = edges[e * 6 + 5];
    const float4* hs4 = (const float4*)(hn + (size_t)sub * 64);
    const float4* ho4 = (const float4*)(hn + (size_t)obj * 64);
    float s = b;
#pragma unroll
    for (int k4 = 0; k4 < 16; k4++) {
      float4 h = hs4[k4];
      s += h.x * fws[k4 * 4 + 0] + h.y * fws[k4 * 4 + 1] + h.z * fws[k4 * 4 + 2] + h.w * fws[k4 * 4 + 3];
      float4 o = ho4[k4];
      s += o.x * fws[64 + k4 * 4 + 0] + o.y * fws[64 + k4 * 4 + 1] + o.z * fws[64 + k4 * 4 + 2] + o.w * fws[64 + k4 * 4 + 3];
    }
    s = (s >= 0.f) ? s : 0.2f * s;
    scores[e] = s;
    if (s > lm) { ls = ls * expf(lm - s) + 1.f; lm = s; }
    else        { ls += expf(s - lm); }
  }
  red_m[threadIdx.x] = lm; red_s[threadIdx.x] = ls;
  __syncthreads();
  for (int d = blockDim.x / 2; d > 0; d >>= 1) {
    if (threadIdx.x < d) {
      float m1 = red_m[threadIdx.x], s1 = red_s[threadIdx.x];
      float m2 = red_m[threadIdx.x + d], s2 = red_s[threadIdx.x + d];
      float m = fmaxf(m1, m2);
      float s = 0.f;
      if (m > -FLT_MAX) s = s1 * expf(m1 - m) + s2 * expf(m2 - m);
      red_m[threadIdx.x] = m; red_s[threadIdx.x] = s;
    }
    __syncthreads();
  }
  if (threadIdx.x == 0) { pmax[blockIdx.x] = red_m[0]; psum[blockIdx.x] = red_s[0]; }
}

// ---------- K9: reduce partials -> gmax, gsum
__global__ void k_softmax_final(const float* __restrict__ pmax, const float* __restrict__ psum,
                                float* __restrict__ scal, int G) {
  __shared__ float red_m[256], red_s[256];
  float lm = -FLT_MAX, ls = 0.f;
  for (int i = threadIdx.x; i < G; i += 256) {
    float m2 = pmax[i], s2 = psum[i];
    if (m2 > lm) { ls = ls * expf(lm - m2) + s2; lm = m2; }
    else         { ls += s2 * expf(m2 - lm); }
  }
  red_m[threadIdx.x] = lm; red_s[threadIdx.x] = ls;
  __syncthreads();
  for (int d = 128; d > 0; d >>= 1) {
    if (threadIdx.x < d) {
      float m1 = red_m[threadIdx.x], s1 = red_s[threadIdx.x];
      float m2 = red_m[threadIdx.x + d], s2 = red_s[threadIdx.x + d];
      float m = fmaxf(m1, m2);
      float s = 0.f;
      if (m > -FLT_MAX) s = s1 * expf(m1 - m) + s2 * expf(m2 - m);
      red_m[threadIdx.x] = m; red_s[threadIdx.x] = s;
    }
    __syncthreads();
  }
  if (threadIdx.x == 0) { scal[0] = red_m[0]; scal[1] = red_s[0]; }
}

// ---------- K10: t[s] = sum w*hn[obj], wsum[s] = sum w  (wave per node via CSR-sub)
__global__ void k_aggsum(const int* __restrict__ edges, const int* __restrict__ off,
                         const int* __restrict__ eid_sub, const float* __restrict__ scores,
                         const float* __restrict__ hn, const float* __restrict__ scal,
                         float* __restrict__ t, float* __restrict__ wsum, int N, int E) {
  int lane = threadIdx.x & 63;
  int widx = threadIdx.x >> 6;
  int node = blockIdx.x * (blockDim.x >> 6) + widx;
  if (node >= N) return;
  float gmax = scal[0];
  float ginv = 1.f / scal[1];
  int b = off[N + node] - E;
  int en = (node == N - 1) ? E : (off[N + node + 1] - E);
  float tacc = 0.f, wacc = 0.f;
  for (int i = b; i < en; i++) {
    int eid = __builtin_amdgcn_readfirstlane(eid_sub[i]);
    int obj = __builtin_amdgcn_readfirstlane(edges[eid * 6 + 5]);
    float w = expf(scores[eid] - gmax);
    tacc += w * hn[(size_t)obj * 64 + lane];
    wacc += w;
  }
  t[(size_t)node * 64 + lane] = tacc * ginv;
  if (lane == 0) wsum[node] = wacc * ginv;
}

// ---------- K11: out = t @ Wnode_w + wsum * Wnode_b
__global__ void k_mm_bias(const float* __restrict__ A, const float* __restrict__ W,
                          const float* __restrict__ bias, const float* __restrict__ wsum,
                          float* __restrict__ C, int N) {
  __shared__ float Wls[4096];
  __shared__ float bls[64];
  for (int i = threadIdx.x; i < 4096; i += blockDim.x) Wls[i] = W[i];
  if (threadIdx.x < 64) bls[threadIdx.x] = bias[threadIdx.x];
  __syncthreads();
  int n = blockIdx.x * blockDim.x + threadIdx.x;
  if (n >= N) return;
  float a[64];
  const float4* A4 = (const float4*)(A + (size_t)n * 64);
#pragma unroll
  for (int k4 = 0; k4 < 16; k4++) {
    float4 h = A4[k4];
    a[k4 * 4 + 0] = h.x; a[k4 * 4 + 1] = h.y; a[k4 * 4 + 2] = h.z; a[k4 * 4 + 3] = h.w;
  }
  float wsn = wsum[n];
  float4* C4 = (float4*)(C + (size_t)n * 64);
#pragma unroll
  for (int c = 0; c < 4; c++) {
    float acc[16];
#pragma unroll
    for (int j = 0; j < 16; j++) acc[j] = wsn * bls[c * 16 + j];
    for (int k = 0; k < 64; k++) {
      float ak = a[k];
#pragma unroll
      for (int j = 0; j < 16; j++) acc[j] += ak * Wls[k * 64 + c * 16 + j];
    }
#pragma unroll
    for (int q = 0; q < 4; q++)
      C4[c * 4 + q] = make_float4(acc[q * 4], acc[q * 4 + 1], acc[q * 4 + 2], acc[q * 4 + 3]);
  }
}

extern "C" void kernel_launch(void* const* d_in, const int* in_sizes, int n_in,
                              void* d_out, int out_size, void* d_ws, size_t ws_size,
                              hipStream_t stream) {
  const float* hidden    = (const float*)d_in[0];
  const float* rela      = (const float*)d_in[1];
  const float* Ws        = (const float*)d_in[2];
  const float* Wr        = (const float*)d_in[3];
  const float* Wqr_w     = (const float*)d_in[4];
  const float* Wqr_b     = (const float*)d_in[5];
  const float* walpha_w  = (const float*)d_in[6];
  const float* walpha_b  = (const float*)d_in[7];
  const float* Wh        = (const float*)d_in[8];
  const float* attn_fc_w = (const float*)d_in[9];
  const float* attn_fc_b = (const float*)d_in[10];
  const float* Wnode_w   = (const float*)d_in[11];
  const float* Wnode_b   = (const float*)d_in[12];
  const int*   q_rel     = (const int*)d_in[14];
  const int*   edges     = (const int*)d_in[15];

  int N = in_sizes[0] / 64;      // 500000
  int E = in_sizes[15] / 6;      // 1000000
  int nrel = in_sizes[1] / 64;   // 401
  int batch = in_sizes[14];      // 32

  char* w = (char*)d_ws;
  size_t o = 0;
  float* region1 = (float*)(w + o); o += (size_t)N * 64 * 4;   // agg, then t
  float* alpha   = (float*)(w + o); o += (size_t)E * 4;
  float* scores  = (float*)(w + o); o += (size_t)E * 4;
  float* wsum    = (float*)(w + o); o += (size_t)N * 4;
  int*   cnt     = (int*)(w + o);   o += (size_t)2 * N * 4;    // counts, then cursors
  int*   off     = (int*)(w + o);   o += (size_t)2 * N * 4;
  int*   eid_obj = (int*)(w + o);   o += (size_t)E * 4;
  int*   eid_sub = (int*)(w + o);   o += (size_t)E * 4;
  int*   part    = (int*)(w + o);   o += 1024 * 4;
  float* pmax    = (float*)(w + o); o += SOFT_G * 4;
  float* psum    = (float*)(w + o); o += SOFT_G * 4;
  float* s2t     = (float*)(w + o); o += (size_t)nrel * 5 * 4;
  float* s3t     = (float*)(w + o); o += (size_t)batch * 5 * 4;
  float* scal    = (float*)(w + o); o += 2 * 4;

  float* hn  = (float*)d_out;   // phase-1 scratch (fully rewritten by K11)
  float* agg = region1;
  float* t   = region1;

  // K0 tables
  k_tables<<<16, 256, 0, stream>>>(rela, Wr, Wqr_w, Wqr_b, q_rel, s2t, s3t, nrel, batch);
  // zero counts
  hipMemsetAsync(cnt, 0, (size_t)2 * N * 4, stream);
  // K2 histogram
  k_hist<<<(E + 255) / 256, 256, 0, stream>>>(edges, cnt, E, N);
  // scan (concatenated obj||sub counts)
  int SCAN_N = 2 * N;
  int nblk = (SCAN_N + SCAN_CHUNK - 1) / SCAN_CHUNK;  // 977 <= 1024
  k_scan_partial<<<nblk, SCAN_BLK, 0, stream>>>(cnt, part, SCAN_N);
  k_scan_top<<<1, 1024, 0, stream>>>(part, nblk);
  k_scan_final<<<nblk, SCAN_BLK, 0, stream>>>(cnt, part, off, SCAN_N);
  // cursors = copy of offsets (reuse cnt)
  hipMemcpyAsync(cnt, off, (size_t)2 * N * 4, hipMemcpyDeviceToDevice, stream);
  // K4 scatter + alpha
  size_t smem4 = (size_t)(320 + nrel * 5 + batch * 5 + 8) * 4;
  k_scatter_alpha<<<(E + 255) / 256, 256, smem4, stream>>>(
      edges, hidden, Ws, s2t, s3t, walpha_w, walpha_b,
      cnt, eid_obj, eid_sub, alpha, E, N, nrel, batch);
  // K6 segment_max -> agg
  k_agg<<<(N + 3) / 4, 256, 0, stream>>>(edges, off, eid_obj, alpha, hidden, rela, agg, N);
  // K7 hn = agg @ Wh  (into d_out)
  k_mm<<<(N + 255) / 256, 256, 0, stream>>>(agg, Wh, hn, N);
  // K8 scores + softmax partials
  k_scores<<<SOFT_G, 256, 0, stream>>>(edges, hn, attn_fc_w, attn_fc_b, scores, pmax, psum, E);
  // K9 global max/sum
  k_softmax_final<<<1, 256, 0, stream>>>(pmax, psum, scal, SOFT_G);
  // K10 weighted segment_sum pre-matmul accumulators
  k_aggsum<<<(N + 3) / 4, 256, 0, stream>>>(edges, off, eid_sub, scores, hn, scal, t, wsum, N, E);
  // K11 out = t @ Wnode_w + wsum*b
  k_mm_bias<<<(N + 255) / 256, 256, 0, stream>>>(t, Wnode_w, Wnode_b, wsum, (float*)d_out, N);
}

// Round 2
// 1482.661 us; speedup vs baseline: 1.0250x; 1.0250x over previous
//
#include <hip/hip_runtime.h>
#include <math.h>
#include <float.h>

// GNN layer, fp32, atomic-based (no CSR).
// K0 k_tables : s2[rel]=rela@Wr, s3[b]=rela[q_rel[b]]@Wqr_w+b      (tiny)
// K1 k_proj   : P = hidden@Ws (N x 5)  +  agg := sentinel 0xFFFFFFFF
// K2 k_edge_max: wave/edge; alpha from P/s2/s3 tables; x=alpha*(hs-hr);
//                segment_max by obj via int/uint atomic trick into agg
// K3 k_mm_fix : hn = fix(agg)@Wh -> d_out; epilogue u=hn.fw[:64], v=hn.fw[64:];
//                zeroes t (aliases agg) and wsum
// K4 k_scores : s=leaky(u[sub]+v[obj]+b); global online-softmax partials
// K5 k_softmax_final : gmax,gsum
// K6 k_edge_sum: wave/edge; w=exp(s-gmax)/gsum; t[sub]+=w*hn[obj]; wsum[sub]+=w
// K7 k_mm_bias : out = t@Wnode_w + wsum*Wnode_b

#define SOFT_G 2048

// ---------- K0
__global__ void k_tables(const float* __restrict__ rela, const float* __restrict__ Wr,
                         const float* __restrict__ Wqr_w, const float* __restrict__ Wqr_b,
                         const int* __restrict__ q_rel,
                         float* __restrict__ s2, float* __restrict__ s3,
                         int nrel, int batch) {
  int tid = blockIdx.x * blockDim.x + threadIdx.x;
  int stride = gridDim.x * blockDim.x;
  for (int idx = tid; idx < nrel * 5; idx += stride) {
    int r = idx / 5, j = idx % 5;
    float acc = 0.f;
    for (int k = 0; k < 64; k++) acc += rela[r * 64 + k] * Wr[k * 5 + j];
    s2[idx] = acc;
  }
  for (int idx = tid; idx < batch * 5; idx += stride) {
    int b = idx / 5, j = idx % 5;
    int qr = q_rel[b];
    float acc = Wqr_b[j];
    for (int k = 0; k < 64; k++) acc += rela[qr * 64 + k] * Wqr_w[k * 5 + j];
    s3[idx] = acc;
  }
}

// ---------- K1: P = hidden @ Ws ; agg := sentinel
__global__ void k_proj(const float* __restrict__ hidden, const float* __restrict__ Ws_g,
                       float* __restrict__ P, uint4* __restrict__ aggq, int N) {
  __shared__ float Ws_s[320];
  for (int i = threadIdx.x; i < 320; i += blockDim.x) Ws_s[i] = Ws_g[i];
  __syncthreads();
  int tid = blockIdx.x * blockDim.x + threadIdx.x;
  // coalesced sentinel fill of agg (N*16 uint4)
  uint4 sent = make_uint4(~0u, ~0u, ~0u, ~0u);
  size_t total = (size_t)N * 16;
  size_t gsz = (size_t)gridDim.x * blockDim.x;
  for (size_t i = tid; i < total; i += gsz) aggq[i] = sent;
  int n = tid;
  if (n >= N) return;
  float hs[64];
  const float4* h4 = (const float4*)(hidden + (size_t)n * 64);
#pragma unroll
  for (int k4 = 0; k4 < 16; k4++) {
    float4 h = h4[k4];
    hs[k4 * 4 + 0] = h.x; hs[k4 * 4 + 1] = h.y; hs[k4 * 4 + 2] = h.z; hs[k4 * 4 + 3] = h.w;
  }
  float acc[5] = {0.f, 0.f, 0.f, 0.f, 0.f};
#pragma unroll 4
  for (int k = 0; k < 64; k++) {
    float h = hs[k];
#pragma unroll
    for (int j = 0; j < 5; j++) acc[j] += h * Ws_s[k * 5 + j];
  }
#pragma unroll
  for (int j = 0; j < 5; j++) P[(size_t)n * 5 + j] = acc[j];
}

// ---------- K2: per-edge alpha + atomic segment_max by obj
__global__ void k_edge_max(const int* __restrict__ edges, const float* __restrict__ P,
                           const float* __restrict__ s2, const float* __restrict__ s3,
                           const float* __restrict__ walpha_w, const float* __restrict__ walpha_b,
                           const float* __restrict__ hidden, const float* __restrict__ rela,
                           float* __restrict__ agg, int E) {
  int lane = threadIdx.x & 63;
  int e = blockIdx.x * (blockDim.x >> 6) + (threadIdx.x >> 6);
  if (e >= E) return;
  e = __builtin_amdgcn_readfirstlane(e);   // wave-uniform -> scalar loads
  int ridx = edges[e * 6 + 0];
  int rel  = edges[e * 6 + 2];
  int sub  = edges[e * 6 + 4];
  int obj  = edges[e * 6 + 5];
  float z = walpha_b[0];
#pragma unroll
  for (int j = 0; j < 5; j++) {
    float vj = P[(size_t)sub * 5 + j] + s2[rel * 5 + j] + s3[ridx * 5 + j];
    z += fmaxf(vj, 0.f) * walpha_w[j];
  }
  float a = 1.f / (1.f + expf(-z));
  float x = a * (hidden[(size_t)sub * 64 + lane] - rela[rel * 64 + lane]);
  float* addr = agg + (size_t)obj * 64 + lane;
  // float-max via int/uint atomics; sentinel 0xFFFFFFFF loses to everything
  if (x >= 0.f) atomicMax((int*)addr, __float_as_int(x));
  else          atomicMin((unsigned int*)addr, __float_as_uint(x));
}

// ---------- K3: hn = fix(agg)@Wh (-> d_out); u/v epilogue; zero t(=agg) and wsum
__global__ void k_mm_fix(float* AT /* agg in, zeroed as t */,
                         const float* __restrict__ W, const float* __restrict__ fw,
                         float* __restrict__ hn, float* __restrict__ u, float* __restrict__ v,
                         float* __restrict__ wsum, int N) {
  __shared__ float Wls[4096];
  __shared__ float fws[128];
  for (int i = threadIdx.x; i < 4096; i += blockDim.x) Wls[i] = W[i];
  for (int i = threadIdx.x; i < 128; i += blockDim.x) fws[i] = fw[i];
  __syncthreads();
  int n = blockIdx.x * blockDim.x + threadIdx.x;
  if (n >= N) return;
  float a[64];
  float4* A4 = (float4*)(AT + (size_t)n * 64);
#pragma unroll
  for (int k4 = 0; k4 < 16; k4++) {
    float4 h = A4[k4];
    float x0 = (__float_as_uint(h.x) == ~0u) ? 0.f : h.x;
    float x1 = (__float_as_uint(h.y) == ~0u) ? 0.f : h.y;
    float x2 = (__float_as_uint(h.z) == ~0u) ? 0.f : h.z;
    float x3 = (__float_as_uint(h.w) == ~0u) ? 0.f : h.w;
    a[k4 * 4 + 0] = x0; a[k4 * 4 + 1] = x1; a[k4 * 4 + 2] = x2; a[k4 * 4 + 3] = x3;
  }
  // zero this row as t (same memory; read-before-write within thread)
  float4 z4 = make_float4(0.f, 0.f, 0.f, 0.f);
#pragma unroll
  for (int k4 = 0; k4 < 16; k4++) A4[k4] = z4;
  wsum[n] = 0.f;
  float uacc = 0.f, vacc = 0.f;
  float4* C4 = (float4*)(hn + (size_t)n * 64);
#pragma unroll
  for (int c = 0; c < 4; c++) {
    float acc[16];
#pragma unroll
    for (int j = 0; j < 16; j++) acc[j] = 0.f;
    for (int k = 0; k < 64; k++) {
      float ak = a[k];
#pragma unroll
      for (int j = 0; j < 16; j++) acc[j] += ak * Wls[k * 64 + c * 16 + j];
    }
#pragma unroll
    for (int j = 0; j < 16; j++) {
      uacc += acc[j] * fws[c * 16 + j];
      vacc += acc[j] * fws[64 + c * 16 + j];
    }
#pragma unroll
    for (int q = 0; q < 4; q++)
      C4[c * 4 + q] = make_float4(acc[q * 4], acc[q * 4 + 1], acc[q * 4 + 2], acc[q * 4 + 3]);
  }
  u[n] = uacc;
  v[n] = vacc;
}

// ---------- K4: scores from u/v tables + online softmax partials
__global__ void k_scores(const int* __restrict__ edges, const float* __restrict__ u,
                         const float* __restrict__ v, const float* __restrict__ fb,
                         float* __restrict__ scores, float* __restrict__ pmax,
                         float* __restrict__ psum, int E) {
  __shared__ float red_m[256], red_s[256];
  float b = fb[0];
  float lm = -FLT_MAX, ls = 0.f;
  for (int e = blockIdx.x * blockDim.x + threadIdx.x; e < E; e += gridDim.x * blockDim.x) {
    int sub = edges[e * 6 + 4], obj = edges[e * 6 + 5];
    float s = u[sub] + v[obj] + b;
    s = (s >= 0.f) ? s : 0.2f * s;
    scores[e] = s;
    if (s > lm) { ls = ls * expf(lm - s) + 1.f; lm = s; }
    else        { ls += expf(s - lm); }
  }
  red_m[threadIdx.x] = lm; red_s[threadIdx.x] = ls;
  __syncthreads();
  for (int d = blockDim.x / 2; d > 0; d >>= 1) {
    if (threadIdx.x < d) {
      float m1 = red_m[threadIdx.x], s1 = red_s[threadIdx.x];
      float m2 = red_m[threadIdx.x + d], s2 = red_s[threadIdx.x + d];
      float m = fmaxf(m1, m2);
      float s = 0.f;
      if (m > -FLT_MAX) s = s1 * expf(m1 - m) + s2 * expf(m2 - m);
      red_m[threadIdx.x] = m; red_s[threadIdx.x] = s;
    }
    __syncthreads();
  }
  if (threadIdx.x == 0) { pmax[blockIdx.x] = red_m[0]; psum[blockIdx.x] = red_s[0]; }
}

// ---------- K5
__global__ void k_softmax_final(const float* __restrict__ pmax, const float* __restrict__ psum,
                                float* __restrict__ scal, int G) {
  __shared__ float red_m[256], red_s[256];
  float lm = -FLT_MAX, ls = 0.f;
  for (int i = threadIdx.x; i < G; i += 256) {
    float m2 = pmax[i], s2 = psum[i];
    if (m2 > lm) { ls = ls * expf(lm - m2) + s2; lm = m2; }
    else         { ls += s2 * expf(m2 - lm); }
  }
  red_m[threadIdx.x] = lm; red_s[threadIdx.x] = ls;
  __syncthreads();
  for (int d = 128; d > 0; d >>= 1) {
    if (threadIdx.x < d) {
      float m1 = red_m[threadIdx.x], s1 = red_s[threadIdx.x];
      float m2 = red_m[threadIdx.x + d], s2 = red_s[threadIdx.x + d];
      float m = fmaxf(m1, m2);
      float s = 0.f;
      if (m > -FLT_MAX) s = s1 * expf(m1 - m) + s2 * expf(m2 - m);
      red_m[threadIdx.x] = m; red_s[threadIdx.x] = s;
    }
    __syncthreads();
  }
  if (threadIdx.x == 0) { scal[0] = red_m[0]; scal[1] = red_s[0]; }
}

// ---------- K6: weighted segment_sum by sub via hw float atomics
__global__ void k_edge_sum(const int* __restrict__ edges, const float* __restrict__ scores,
                           const float* __restrict__ scal, const float* __restrict__ hn,
                           float* __restrict__ t, float* __restrict__ wsum, int E) {
  int lane = threadIdx.x & 63;
  int e = blockIdx.x * (blockDim.x >> 6) + (threadIdx.x >> 6);
  if (e >= E) return;
  e = __builtin_amdgcn_readfirstlane(e);
  int sub = edges[e * 6 + 4];
  int obj = edges[e * 6 + 5];
  float w = expf(scores[e] - scal[0]) / scal[1];
  atomicAdd(t + (size_t)sub * 64 + lane, w * hn[(size_t)obj * 64 + lane]);
  if (lane == 0) atomicAdd(wsum + sub, w);
}

// ---------- K7: out = t @ Wnode_w + wsum * Wnode_b
__global__ void k_mm_bias(const float* __restrict__ A, const float* __restrict__ W,
                          const float* __restrict__ bias, const float* __restrict__ wsum,
                          float* __restrict__ C, int N) {
  __shared__ float Wls[4096];
  __shared__ float bls[64];
  for (int i = threadIdx.x; i < 4096; i += blockDim.x) Wls[i] = W[i];
  if (threadIdx.x < 64) bls[threadIdx.x] = bias[threadIdx.x];
  __syncthreads();
  int n = blockIdx.x * blockDim.x + threadIdx.x;
  if (n >= N) return;
  float a[64];
  const float4* A4 = (const float4*)(A + (size_t)n * 64);
#pragma unroll
  for (int k4 = 0; k4 < 16; k4++) {
    float4 h = A4[k4];
    a[k4 * 4 + 0] = h.x; a[k4 * 4 + 1] = h.y; a[k4 * 4 + 2] = h.z; a[k4 * 4 + 3] = h.w;
  }
  float wsn = wsum[n];
  float4* C4 = (float4*)(C + (size_t)n * 64);
#pragma unroll
  for (int c = 0; c < 4; c++) {
    float acc[16];
#pragma unroll
    for (int j = 0; j < 16; j++) acc[j] = wsn * bls[c * 16 + j];
    for (int k = 0; k < 64; k++) {
      float ak = a[k];
#pragma unroll
      for (int j = 0; j < 16; j++) acc[j] += ak * Wls[k * 64 + c * 16 + j];
    }
#pragma unroll
    for (int q = 0; q < 4; q++)
      C4[c * 4 + q] = make_float4(acc[q * 4], acc[q * 4 + 1], acc[q * 4 + 2], acc[q * 4 + 3]);
  }
}

extern "C" void kernel_launch(void* const* d_in, const int* in_sizes, int n_in,
                              void* d_out, int out_size, void* d_ws, size_t ws_size,
                              hipStream_t stream) {
  const float* hidden    = (const float*)d_in[0];
  const float* rela      = (const float*)d_in[1];
  const float* Ws        = (const float*)d_in[2];
  const float* Wr        = (const float*)d_in[3];
  const float* Wqr_w     = (const float*)d_in[4];
  const float* Wqr_b     = (const float*)d_in[5];
  const float* walpha_w  = (const float*)d_in[6];
  const float* walpha_b  = (const float*)d_in[7];
  const float* Wh        = (const float*)d_in[8];
  const float* attn_fc_w = (const float*)d_in[9];
  const float* attn_fc_b = (const float*)d_in[10];
  const float* Wnode_w   = (const float*)d_in[11];
  const float* Wnode_b   = (const float*)d_in[12];
  const int*   q_rel     = (const int*)d_in[14];
  const int*   edges     = (const int*)d_in[15];

  int N = in_sizes[0] / 64;      // 500000
  int E = in_sizes[15] / 6;      // 1000000
  int nrel = in_sizes[1] / 64;   // 401
  int batch = in_sizes[14];      // 32

  char* w = (char*)d_ws;
  size_t o = 0;
  float* aggT   = (float*)(w + o); o += (size_t)N * 64 * 4;  // agg, then t (aliased)
  float* P      = (float*)(w + o); o += (size_t)N * 5 * 4;
  float* u      = (float*)(w + o); o += (size_t)N * 4;
  float* v      = (float*)(w + o); o += (size_t)N * 4;
  float* scores = (float*)(w + o); o += (size_t)E * 4;
  float* wsum   = (float*)(w + o); o += (size_t)N * 4;
  float* s2t    = (float*)(w + o); o += (size_t)nrel * 5 * 4;
  float* s3t    = (float*)(w + o); o += (size_t)batch * 5 * 4;
  float* pmax   = (float*)(w + o); o += SOFT_G * 4;
  float* psum   = (float*)(w + o); o += SOFT_G * 4;
  float* scal   = (float*)(w + o); o += 2 * 4;

  float* hn = (float*)d_out;  // phase-1 result lives in d_out until K7 overwrites

  k_tables<<<16, 256, 0, stream>>>(rela, Wr, Wqr_w, Wqr_b, q_rel, s2t, s3t, nrel, batch);
  k_proj<<<(N + 255) / 256, 256, 0, stream>>>(hidden, Ws, P, (uint4*)aggT, N);
  k_edge_max<<<(E + 3) / 4, 256, 0, stream>>>(edges, P, s2t, s3t, walpha_w, walpha_b,
                                              hidden, rela, aggT, E);
  k_mm_fix<<<(N + 255) / 256, 256, 0, stream>>>(aggT, Wh, attn_fc_w, hn, u, v, wsum, N);
  k_scores<<<SOFT_G, 256, 0, stream>>>(edges, u, v, attn_fc_b, scores, pmax, psum, E);
  k_softmax_final<<<1, 256, 0, stream>>>(pmax, psum, scal, SOFT_G);
  k_edge_sum<<<(E + 3) / 4, 256, 0, stream>>>(edges, scores, scal, hn, aggT /*t*/, wsum, E);
  k_mm_bias<<<(N + 255) / 256, 256, 0, stream>>>(aggT /*t*/, Wnode_w, Wnode_b, wsum,
                                                 (float*)d_out, N);
}

// Round 3
// 1167.334 us; speedup vs baseline: 1.3019x; 1.2701x over previous
//
#include <hip/hip_runtime.h>
#include <math.h>
#include <float.h>

// GNN layer, fp32, atomic-based (no CSR).
// K0 k_tables : s2[rel]=rela@Wr, s3[b]=rela[q_rel[b]]@Wqr_w+b      (tiny)
// K1 k_proj   : P = hidden@Ws (N x 5)  +  agg := sentinel 0xFFFFFFFF
// K2 k_edge_max: wave/edge; alpha from P/s2/s3 tables; x=alpha*(hs-hr);
//                segment_max by obj via int/uint atomic trick into agg
// K3 k_mm_fix : hn = fix(agg)@Wh -> d_out; epilogue u=hn.fw[:64], v=hn.fw[64:];
//                zeroes t (aliases agg) and wsum. Register-resident (no spill):
//                __launch_bounds__(256,2), acc[64]+a[64] in VGPRs, W via s_load.
// K4 k_scores : s=leaky(u[sub]+v[obj]+b); global online-softmax partials
// K5 k_softmax_final : gmax,gsum
// K6 k_edge_sum: wave/edge; w=exp(s-gmax)/gsum; t[sub]+=w*hn[obj]; wsum[sub]+=w
// K7 k_mm_bias : out = t@Wnode_w + wsum*Wnode_b  (same no-spill structure)

#define SOFT_G 2048

// ---------- K0
__global__ void k_tables(const float* __restrict__ rela, const float* __restrict__ Wr,
                         const float* __restrict__ Wqr_w, const float* __restrict__ Wqr_b,
                         const int* __restrict__ q_rel,
                         float* __restrict__ s2, float* __restrict__ s3,
                         int nrel, int batch) {
  int tid = blockIdx.x * blockDim.x + threadIdx.x;
  int stride = gridDim.x * blockDim.x;
  for (int idx = tid; idx < nrel * 5; idx += stride) {
    int r = idx / 5, j = idx % 5;
    float acc = 0.f;
    for (int k = 0; k < 64; k++) acc += rela[r * 64 + k] * Wr[k * 5 + j];
    s2[idx] = acc;
  }
  for (int idx = tid; idx < batch * 5; idx += stride) {
    int b = idx / 5, j = idx % 5;
    int qr = q_rel[b];
    float acc = Wqr_b[j];
    for (int k = 0; k < 64; k++) acc += rela[qr * 64 + k] * Wqr_w[k * 5 + j];
    s3[idx] = acc;
  }
}

// ---------- K1: P = hidden @ Ws ; agg := sentinel
__global__ void __launch_bounds__(256, 2)
k_proj(const float* __restrict__ hidden, const float* __restrict__ Ws_g,
       float* __restrict__ P, uint4* __restrict__ aggq, int N) {
  int tid = blockIdx.x * blockDim.x + threadIdx.x;
  // coalesced sentinel fill of agg (N*16 uint4)
  uint4 sent = make_uint4(~0u, ~0u, ~0u, ~0u);
  size_t total = (size_t)N * 16;
  size_t gsz = (size_t)gridDim.x * blockDim.x;
  for (size_t i = tid; i < total; i += gsz) aggq[i] = sent;
  int n = tid;
  if (n >= N) return;
  float hs[64];
  const float4* h4 = (const float4*)(hidden + (size_t)n * 64);
#pragma unroll
  for (int k4 = 0; k4 < 16; k4++) {
    float4 h = h4[k4];
    hs[k4 * 4 + 0] = h.x; hs[k4 * 4 + 1] = h.y; hs[k4 * 4 + 2] = h.z; hs[k4 * 4 + 3] = h.w;
  }
  float acc[5] = {0.f, 0.f, 0.f, 0.f, 0.f};
#pragma unroll
  for (int k = 0; k < 64; k++) {
    float h = hs[k];
#pragma unroll
    for (int j = 0; j < 5; j++) acc[j] += h * Ws_g[k * 5 + j];  // uniform idx -> s_load
  }
#pragma unroll
  for (int j = 0; j < 5; j++) P[(size_t)n * 5 + j] = acc[j];
}

// ---------- K2: per-edge alpha + atomic segment_max by obj
__global__ void k_edge_max(const int* __restrict__ edges, const float* __restrict__ P,
                           const float* __restrict__ s2, const float* __restrict__ s3,
                           const float* __restrict__ walpha_w, const float* __restrict__ walpha_b,
                           const float* __restrict__ hidden, const float* __restrict__ rela,
                           float* __restrict__ agg, int E) {
  int lane = threadIdx.x & 63;
  int e = blockIdx.x * (blockDim.x >> 6) + (threadIdx.x >> 6);
  if (e >= E) return;
  e = __builtin_amdgcn_readfirstlane(e);   // wave-uniform -> scalar loads
  int ridx = edges[e * 6 + 0];
  int rel  = edges[e * 6 + 2];
  int sub  = edges[e * 6 + 4];
  int obj  = edges[e * 6 + 5];
  float z = walpha_b[0];
#pragma unroll
  for (int j = 0; j < 5; j++) {
    float vj = P[(size_t)sub * 5 + j] + s2[rel * 5 + j] + s3[ridx * 5 + j];
    z += fmaxf(vj, 0.f) * walpha_w[j];
  }
  float a = 1.f / (1.f + expf(-z));
  float x = a * (hidden[(size_t)sub * 64 + lane] - rela[rel * 64 + lane]);
  float* addr = agg + (size_t)obj * 64 + lane;
  // float-max via int/uint atomics; sentinel 0xFFFFFFFF loses to everything
  if (x >= 0.f) atomicMax((int*)addr, __float_as_int(x));
  else          atomicMin((unsigned int*)addr, __float_as_uint(x));
}

// ---------- K3: hn = fix(agg)@Wh (-> d_out); u/v epilogue; zero t(=agg) and wsum
__global__ void __launch_bounds__(256, 2)
k_mm_fix(float* __restrict__ AT /* agg in, zeroed as t */,
         const float* __restrict__ W, const float* __restrict__ fw,
         float* __restrict__ hn, float* __restrict__ u, float* __restrict__ v,
         float* __restrict__ wsum, int N) {
  int n = blockIdx.x * blockDim.x + threadIdx.x;
  if (n >= N) return;
  float a[64];
  float4* A4 = (float4*)(AT + (size_t)n * 64);
#pragma unroll
  for (int k4 = 0; k4 < 16; k4++) {          // tight read burst
    float4 h = A4[k4];
    a[k4 * 4 + 0] = (__float_as_uint(h.x) == ~0u) ? 0.f : h.x;
    a[k4 * 4 + 1] = (__float_as_uint(h.y) == ~0u) ? 0.f : h.y;
    a[k4 * 4 + 2] = (__float_as_uint(h.z) == ~0u) ? 0.f : h.z;
    a[k4 * 4 + 3] = (__float_as_uint(h.w) == ~0u) ? 0.f : h.w;
  }
  float4 z4 = make_float4(0.f, 0.f, 0.f, 0.f);
#pragma unroll
  for (int k4 = 0; k4 < 16; k4++) A4[k4] = z4;  // tight zero burst (t := 0)
  float acc[64];
#pragma unroll
  for (int j = 0; j < 64; j++) acc[j] = 0.f;
#pragma unroll
  for (int k = 0; k < 64; k++) {
    float ak = a[k];
#pragma unroll
    for (int j = 0; j < 64; j++) acc[j] += ak * W[k * 64 + j];  // uniform -> s_load
  }
  float uacc = 0.f, vacc = 0.f;
#pragma unroll
  for (int j = 0; j < 64; j++) {
    uacc += acc[j] * fw[j];
    vacc += acc[j] * fw[64 + j];
  }
  float4* C4 = (float4*)(hn + (size_t)n * 64);
#pragma unroll
  for (int q = 0; q < 16; q++)               // tight write burst
    C4[q] = make_float4(acc[q * 4], acc[q * 4 + 1], acc[q * 4 + 2], acc[q * 4 + 3]);
  u[n] = uacc;
  v[n] = vacc;
  wsum[n] = 0.f;
}

// ---------- K4: scores from u/v tables + online softmax partials
__global__ void k_scores(const int* __restrict__ edges, const float* __restrict__ u,
                         const float* __restrict__ v, const float* __restrict__ fb,
                         float* __restrict__ scores, float* __restrict__ pmax,
                         float* __restrict__ psum, int E) {
  __shared__ float red_m[256], red_s[256];
  float b = fb[0];
  float lm = -FLT_MAX, ls = 0.f;
  for (int e = blockIdx.x * blockDim.x + threadIdx.x; e < E; e += gridDim.x * blockDim.x) {
    int sub = edges[e * 6 + 4], obj = edges[e * 6 + 5];
    float s = u[sub] + v[obj] + b;
    s = (s >= 0.f) ? s : 0.2f * s;
    scores[e] = s;
    if (s > lm) { ls = ls * expf(lm - s) + 1.f; lm = s; }
    else        { ls += expf(s - lm); }
  }
  red_m[threadIdx.x] = lm; red_s[threadIdx.x] = ls;
  __syncthreads();
  for (int d = blockDim.x / 2; d > 0; d >>= 1) {
    if (threadIdx.x < d) {
      float m1 = red_m[threadIdx.x], s1 = red_s[threadIdx.x];
      float m2 = red_m[threadIdx.x + d], s2 = red_s[threadIdx.x + d];
      float m = fmaxf(m1, m2);
      float s = 0.f;
      if (m > -FLT_MAX) s = s1 * expf(m1 - m) + s2 * expf(m2 - m);
      red_m[threadIdx.x] = m; red_s[threadIdx.x] = s;
    }
    __syncthreads();
  }
  if (threadIdx.x == 0) { pmax[blockIdx.x] = red_m[0]; psum[blockIdx.x] = red_s[0]; }
}

// ---------- K5
__global__ void k_softmax_final(const float* __restrict__ pmax, const float* __restrict__ psum,
                                float* __restrict__ scal, int G) {
  __shared__ float red_m[256], red_s[256];
  float lm = -FLT_MAX, ls = 0.f;
  for (int i = threadIdx.x; i < G; i += 256) {
    float m2 = pmax[i], s2 = psum[i];
    if (m2 > lm) { ls = ls * expf(lm - m2) + s2; lm = m2; }
    else         { ls += s2 * expf(m2 - lm); }
  }
  red_m[threadIdx.x] = lm; red_s[threadIdx.x] = ls;
  __syncthreads();
  for (int d = 128; d > 0; d >>= 1) {
    if (threadIdx.x < d) {
      float m1 = red_m[threadIdx.x], s1 = red_s[threadIdx.x];
      float m2 = red_m[threadIdx.x + d], s2 = red_s[threadIdx.x + d];
      float m = fmaxf(m1, m2);
      float s = 0.f;
      if (m > -FLT_MAX) s = s1 * expf(m1 - m) + s2 * expf(m2 - m);
      red_m[threadIdx.x] = m; red_s[threadIdx.x] = s;
    }
    __syncthreads();
  }
  if (threadIdx.x == 0) { scal[0] = red_m[0]; scal[1] = red_s[0]; }
}

// ---------- K6: weighted segment_sum by sub via hw float atomics
__global__ void k_edge_sum(const int* __restrict__ edges, const float* __restrict__ scores,
                           const float* __restrict__ scal, const float* __restrict__ hn,
                           float* __restrict__ t, float* __restrict__ wsum, int E) {
  int lane = threadIdx.x & 63;
  int e = blockIdx.x * (blockDim.x >> 6) + (threadIdx.x >> 6);
  if (e >= E) return;
  e = __builtin_amdgcn_readfirstlane(e);
  int sub = edges[e * 6 + 4];
  int obj = edges[e * 6 + 5];
  float w = expf(scores[e] - scal[0]) / scal[1];
  atomicAdd(t + (size_t)sub * 64 + lane, w * hn[(size_t)obj * 64 + lane]);
  if (lane == 0) atomicAdd(wsum + sub, w);
}

// ---------- K7: out = t @ Wnode_w + wsum * Wnode_b
__global__ void __launch_bounds__(256, 2)
k_mm_bias(const float* __restrict__ A, const float* __restrict__ W,
          const float* __restrict__ bias, const float* __restrict__ wsum,
          float* __restrict__ C, int N) {
  int n = blockIdx.x * blockDim.x + threadIdx.x;
  if (n >= N) return;
  float a[64];
  const float4* A4 = (const float4*)(A + (size_t)n * 64);
#pragma unroll
  for (int k4 = 0; k4 < 16; k4++) {
    float4 h = A4[k4];
    a[k4 * 4 + 0] = h.x; a[k4 * 4 + 1] = h.y; a[k4 * 4 + 2] = h.z; a[k4 * 4 + 3] = h.w;
  }
  float wsn = wsum[n];
  float acc[64];
#pragma unroll
  for (int j = 0; j < 64; j++) acc[j] = wsn * bias[j];  // uniform -> s_load
#pragma unroll
  for (int k = 0; k < 64; k++) {
    float ak = a[k];
#pragma unroll
    for (int j = 0; j < 64; j++) acc[j] += ak * W[k * 64 + j];  // uniform -> s_load
  }
  float4* C4 = (float4*)(C + (size_t)n * 64);
#pragma unroll
  for (int q = 0; q < 16; q++)
    C4[q] = make_float4(acc[q * 4], acc[q * 4 + 1], acc[q * 4 + 2], acc[q * 4 + 3]);
}

extern "C" void kernel_launch(void* const* d_in, const int* in_sizes, int n_in,
                              void* d_out, int out_size, void* d_ws, size_t ws_size,
                              hipStream_t stream) {
  const float* hidden    = (const float*)d_in[0];
  const float* rela      = (const float*)d_in[1];
  const float* Ws        = (const float*)d_in[2];
  const float* Wr        = (const float*)d_in[3];
  const float* Wqr_w     = (const float*)d_in[4];
  const float* Wqr_b     = (const float*)d_in[5];
  const float* walpha_w  = (const float*)d_in[6];
  const float* walpha_b  = (const float*)d_in[7];
  const float* Wh        = (const float*)d_in[8];
  const float* attn_fc_w = (const float*)d_in[9];
  const float* attn_fc_b = (const float*)d_in[10];
  const float* Wnode_w   = (const float*)d_in[11];
  const float* Wnode_b   = (const float*)d_in[12];
  const int*   q_rel     = (const int*)d_in[14];
  const int*   edges     = (const int*)d_in[15];

  int N = in_sizes[0] / 64;      // 500000
  int E = in_sizes[15] / 6;      // 1000000
  int nrel = in_sizes[1] / 64;   // 401
  int batch = in_sizes[14];      // 32

  char* w = (char*)d_ws;
  size_t o = 0;
  float* aggT   = (float*)(w + o); o += (size_t)N * 64 * 4;  // agg, then t (aliased)
  float* P      = (float*)(w + o); o += (size_t)N * 5 * 4;
  float* u      = (float*)(w + o); o += (size_t)N * 4;
  float* v      = (float*)(w + o); o += (size_t)N * 4;
  float* scores = (float*)(w + o); o += (size_t)E * 4;
  float* wsum   = (float*)(w + o); o += (size_t)N * 4;
  float* s2t    = (float*)(w + o); o += (size_t)nrel * 5 * 4;
  float* s3t    = (float*)(w + o); o += (size_t)batch * 5 * 4;
  float* pmax   = (float*)(w + o); o += SOFT_G * 4;
  float* psum   = (float*)(w + o); o += SOFT_G * 4;
  float* scal   = (float*)(w + o); o += 2 * 4;

  float* hn = (float*)d_out;  // phase-1 result lives in d_out until K7 overwrites

  k_tables<<<16, 256, 0, stream>>>(rela, Wr, Wqr_w, Wqr_b, q_rel, s2t, s3t, nrel, batch);
  k_proj<<<(N + 255) / 256, 256, 0, stream>>>(hidden, Ws, P, (uint4*)aggT, N);
  k_edge_max<<<(E + 3) / 4, 256, 0, stream>>>(edges, P, s2t, s3t, walpha_w, walpha_b,
                                              hidden, rela, aggT, E);
  k_mm_fix<<<(N + 255) / 256, 256, 0, stream>>>(aggT, Wh, attn_fc_w, hn, u, v, wsum, N);
  k_scores<<<SOFT_G, 256, 0, stream>>>(edges, u, v, attn_fc_b, scores, pmax, psum, E);
  k_softmax_final<<<1, 256, 0, stream>>>(pmax, psum, scal, SOFT_G);
  k_edge_sum<<<(E + 3) / 4, 256, 0, stream>>>(edges, scores, scal, hn, aggT /*t*/, wsum, E);
  k_mm_bias<<<(N + 255) / 256, 256, 0, stream>>>(aggT /*t*/, Wnode_w, Wnode_b, wsum,
                                                 (float*)d_out, N);
}

// Round 4
// 1048.475 us; speedup vs baseline: 1.4495x; 1.1134x over previous
//
#include <hip/hip_runtime.h>
#include <math.h>
#include <float.h>

// GNN layer, fp32, lean-CSR (atomic-free segment reductions).
// K0 k_tables : s2[rel]=rela@Wr, s3[b]=rela[q_rel[b]]@Wqr_w+b          (tiny)
// K1 k_proj   : P = hidden@Ws (N x 5)
// K2 k_hist   : cnt[obj]++, cnt[N+sub]++
// K3 scan     : exclusive scan of cnt (2N, concatenated) -> off; off[N]==E
// K4 k_scatter: per edge: alpha from P/s2/s3; rec_obj[p]={sub,rel,alpha},
//               rec_sub[q]={obj,sub}  (cursor atomics on copy of off)
// K5 k_agg    : wave/node (by obj-CSR): max over edges of alpha*(hs-hr) -> agg (clean write)
// K6 k_mm_uv  : hn = agg@Wh -> d_out; epilogue u=hn.fw[:64], v=hn.fw[64:]
// K7 k_scores : stream rec_sub: s=leaky(u[sub]+v[obj]+b) -> scores[pos]; softmax partials
// K8 k_softmax_final : gmax, gsum
// K9 k_aggsum : wave/node (by sub-CSR): t=sum w*hn[obj], wsum=sum w (unnormalized)
// K10 k_mm_bias: out = (t@Wnode_w + wsum*Wnode_b) / gsum

#define SCAN_BLK 256
#define SCAN_ITEMS 4
#define SCAN_CHUNK (SCAN_BLK * SCAN_ITEMS)
#define SOFT_G 2048

// ---------- K0
__global__ void k_tables(const float* __restrict__ rela, const float* __restrict__ Wr,
                         const float* __restrict__ Wqr_w, const float* __restrict__ Wqr_b,
                         const int* __restrict__ q_rel,
                         float* __restrict__ s2, float* __restrict__ s3,
                         int nrel, int batch) {
  int tid = blockIdx.x * blockDim.x + threadIdx.x;
  int stride = gridDim.x * blockDim.x;
  for (int idx = tid; idx < nrel * 5; idx += stride) {
    int r = idx / 5, j = idx % 5;
    float acc = 0.f;
    for (int k = 0; k < 64; k++) acc += rela[r * 64 + k] * Wr[k * 5 + j];
    s2[idx] = acc;
  }
  for (int idx = tid; idx < batch * 5; idx += stride) {
    int b = idx / 5, j = idx % 5;
    int qr = q_rel[b];
    float acc = Wqr_b[j];
    for (int k = 0; k < 64; k++) acc += rela[qr * 64 + k] * Wqr_w[k * 5 + j];
    s3[idx] = acc;
  }
}

// ---------- K1: P = hidden @ Ws
__global__ void __launch_bounds__(256, 2)
k_proj(const float* __restrict__ hidden, const float* __restrict__ Ws_g,
       float* __restrict__ P, int N) {
  int n = blockIdx.x * blockDim.x + threadIdx.x;
  if (n >= N) return;
  float hs[64];
  const float4* h4 = (const float4*)(hidden + (size_t)n * 64);
#pragma unroll
  for (int k4 = 0; k4 < 16; k4++) {
    float4 h = h4[k4];
    hs[k4 * 4 + 0] = h.x; hs[k4 * 4 + 1] = h.y; hs[k4 * 4 + 2] = h.z; hs[k4 * 4 + 3] = h.w;
  }
  float acc[5] = {0.f, 0.f, 0.f, 0.f, 0.f};
#pragma unroll
  for (int k = 0; k < 64; k++) {
    float h = hs[k];
#pragma unroll
    for (int j = 0; j < 5; j++) acc[j] += h * Ws_g[k * 5 + j];  // uniform idx -> s_load
  }
#pragma unroll
  for (int j = 0; j < 5; j++) P[(size_t)n * 5 + j] = acc[j];
}

// ---------- K2
__global__ void k_hist(const int* __restrict__ edges, int* __restrict__ cnt, int E, int N) {
  int e = blockIdx.x * blockDim.x + threadIdx.x;
  if (e < E) {
    int sub = edges[e * 6 + 4];
    int obj = edges[e * 6 + 5];
    atomicAdd(&cnt[obj], 1);
    atomicAdd(&cnt[N + sub], 1);
  }
}

// ---------- K3a
__global__ void k_scan_partial(const int* __restrict__ cnt, int* __restrict__ part, int n) {
  __shared__ int sdata[SCAN_BLK];
  int base = blockIdx.x * SCAN_CHUNK + threadIdx.x * SCAN_ITEMS;
  int s = 0;
#pragma unroll
  for (int j = 0; j < SCAN_ITEMS; j++) { int i = base + j; if (i < n) s += cnt[i]; }
  sdata[threadIdx.x] = s;
  __syncthreads();
  for (int d = SCAN_BLK / 2; d > 0; d >>= 1) {
    if (threadIdx.x < d) sdata[threadIdx.x] += sdata[threadIdx.x + d];
    __syncthreads();
  }
  if (threadIdx.x == 0) part[blockIdx.x] = sdata[0];
}

// ---------- K3b (nblk <= 1024)
__global__ void k_scan_top(int* part, int nblk) {
  __shared__ int lds[1024];
  int tid = threadIdx.x;
  int v = (tid < nblk) ? part[tid] : 0;
  lds[tid] = v;
  __syncthreads();
  for (int d = 1; d < 1024; d <<= 1) {
    int t = (tid >= d) ? lds[tid - d] : 0;
    __syncthreads();
    lds[tid] += t;
    __syncthreads();
  }
  if (tid < nblk) part[tid] = lds[tid] - v;  // exclusive
}

// ---------- K3c
__global__ void k_scan_final(const int* __restrict__ cnt, const int* __restrict__ part,
                             int* __restrict__ off, int n) {
  __shared__ int lds[SCAN_BLK];
  int tid = threadIdx.x;
  int base = blockIdx.x * SCAN_CHUNK + tid * SCAN_ITEMS;
  int c[SCAN_ITEMS];
  int s = 0;
#pragma unroll
  for (int j = 0; j < SCAN_ITEMS; j++) { int i = base + j; c[j] = (i < n) ? cnt[i] : 0; s += c[j]; }
  int v = s;
  lds[tid] = s;
  __syncthreads();
  for (int d = 1; d < SCAN_BLK; d <<= 1) {
    int t = (tid >= d) ? lds[tid - d] : 0;
    __syncthreads();
    lds[tid] += t;
    __syncthreads();
  }
  int run = part[blockIdx.x] + (lds[tid] - v);
#pragma unroll
  for (int j = 0; j < SCAN_ITEMS; j++) { int i = base + j; if (i < n) off[i] = run; run += c[j]; }
}

// ---------- K4: alpha + scatter packed records
__global__ void k_scatter(const int* __restrict__ edges, const float* __restrict__ P,
                          const float* __restrict__ s2, const float* __restrict__ s3,
                          const float* __restrict__ walpha_w, const float* __restrict__ walpha_b,
                          int* __restrict__ cur, int4* __restrict__ rec_obj,
                          int2* __restrict__ rec_sub, int E, int N) {
  int e = blockIdx.x * blockDim.x + threadIdx.x;
  if (e >= E) return;
  int ridx = edges[e * 6 + 0];
  int rel  = edges[e * 6 + 2];
  int sub  = edges[e * 6 + 4];
  int obj  = edges[e * 6 + 5];
  float z = walpha_b[0];
#pragma unroll
  for (int j = 0; j < 5; j++) {
    float vj = P[(size_t)sub * 5 + j] + s2[rel * 5 + j] + s3[ridx * 5 + j];
    z += fmaxf(vj, 0.f) * walpha_w[j];
  }
  float a = 1.f / (1.f + expf(-z));
  int p = atomicAdd(&cur[obj], 1);
  rec_obj[p] = make_int4(sub, rel, __float_as_int(a), 0);
  int q = atomicAdd(&cur[N + sub], 1) - E;
  rec_sub[q] = make_int2(obj, sub);
}

// ---------- K5: segment_max by obj (atomic-free, wave/node)
__global__ void k_agg(const int* __restrict__ off, const int4* __restrict__ rec_obj,
                      const float* __restrict__ hidden, const float* __restrict__ rela,
                      float* __restrict__ agg, int N) {
  int lane = threadIdx.x & 63;
  int node = blockIdx.x * (blockDim.x >> 6) + (threadIdx.x >> 6);
  if (node >= N) return;
  int b = off[node], en = off[node + 1];  // off[N] == E
  float vmax = -FLT_MAX;
  for (int base = b; base < en; base += 64) {
    int cnt = min(64, en - base);
    int4 r = make_int4(0, 0, 0, 0);
    if (lane < cnt) r = rec_obj[base + lane];
    for (int i = 0; i < cnt; i++) {
      int sub = __shfl(r.x, i);
      int rel = __shfl(r.y, i);
      float a = __int_as_float(__shfl(r.z, i));
      float x = a * (hidden[(size_t)sub * 64 + lane] - rela[rel * 64 + lane]);
      vmax = fmaxf(vmax, x);
    }
  }
  agg[(size_t)node * 64 + lane] = (en > b) ? vmax : 0.f;
}

// ---------- K6: hn = agg@Wh -> d_out; u/v epilogue
__global__ void __launch_bounds__(256, 2)
k_mm_uv(const float* __restrict__ A, const float* __restrict__ W, const float* __restrict__ fw,
        float* __restrict__ hn, float* __restrict__ u, float* __restrict__ v, int N) {
  int n = blockIdx.x * blockDim.x + threadIdx.x;
  if (n >= N) return;
  float a[64];
  const float4* A4 = (const float4*)(A + (size_t)n * 64);
#pragma unroll
  for (int k4 = 0; k4 < 16; k4++) {
    float4 h = A4[k4];
    a[k4 * 4 + 0] = h.x; a[k4 * 4 + 1] = h.y; a[k4 * 4 + 2] = h.z; a[k4 * 4 + 3] = h.w;
  }
  float acc[64];
#pragma unroll
  for (int j = 0; j < 64; j++) acc[j] = 0.f;
#pragma unroll
  for (int k = 0; k < 64; k++) {
    float ak = a[k];
#pragma unroll
    for (int j = 0; j < 64; j++) acc[j] += ak * W[k * 64 + j];  // uniform -> s_load
  }
  float uacc = 0.f, vacc = 0.f;
#pragma unroll
  for (int j = 0; j < 64; j++) {
    uacc += acc[j] * fw[j];
    vacc += acc[j] * fw[64 + j];
  }
  float4* C4 = (float4*)(hn + (size_t)n * 64);
#pragma unroll
  for (int q = 0; q < 16; q++)
    C4[q] = make_float4(acc[q * 4], acc[q * 4 + 1], acc[q * 4 + 2], acc[q * 4 + 3]);
  u[n] = uacc;
  v[n] = vacc;
}

// ---------- K7: scores in sub-CSR position order + softmax partials
__global__ void k_scores(const int2* __restrict__ rec_sub, const float* __restrict__ u,
                         const float* __restrict__ v, const float* __restrict__ fb,
                         float* __restrict__ scores, float* __restrict__ pmax,
                         float* __restrict__ psum, int E) {
  __shared__ float red_m[256], red_s[256];
  float b = fb[0];
  float lm = -FLT_MAX, ls = 0.f;
  for (int pos = blockIdx.x * blockDim.x + threadIdx.x; pos < E; pos += gridDim.x * blockDim.x) {
    int2 r = rec_sub[pos];
    float s = u[r.y] + v[r.x] + b;
    s = (s >= 0.f) ? s : 0.2f * s;
    scores[pos] = s;
    if (s > lm) { ls = ls * expf(lm - s) + 1.f; lm = s; }
    else        { ls += expf(s - lm); }
  }
  red_m[threadIdx.x] = lm; red_s[threadIdx.x] = ls;
  __syncthreads();
  for (int d = blockDim.x / 2; d > 0; d >>= 1) {
    if (threadIdx.x < d) {
      float m1 = red_m[threadIdx.x], s1 = red_s[threadIdx.x];
      float m2 = red_m[threadIdx.x + d], s2 = red_s[threadIdx.x + d];
      float m = fmaxf(m1, m2);
      float s = 0.f;
      if (m > -FLT_MAX) s = s1 * expf(m1 - m) + s2 * expf(m2 - m);
      red_m[threadIdx.x] = m; red_s[threadIdx.x] = s;
    }
    __syncthreads();
  }
  if (threadIdx.x == 0) { pmax[blockIdx.x] = red_m[0]; psum[blockIdx.x] = red_s[0]; }
}

// ---------- K8
__global__ void k_softmax_final(const float* __restrict__ pmax, const float* __restrict__ psum,
                                float* __restrict__ scal, int G) {
  __shared__ float red_m[256], red_s[256];
  float lm = -FLT_MAX, ls = 0.f;
  for (int i = threadIdx.x; i < G; i += 256) {
    float m2 = pmax[i], s2 = psum[i];
    if (m2 > lm) { ls = ls * expf(lm - m2) + s2; lm = m2; }
    else         { ls += s2 * expf(m2 - lm); }
  }
  red_m[threadIdx.x] = lm; red_s[threadIdx.x] = ls;
  __syncthreads();
  for (int d = 128; d > 0; d >>= 1) {
    if (threadIdx.x < d) {
      float m1 = red_m[threadIdx.x], s1 = red_s[threadIdx.x];
      float m2 = red_m[threadIdx.x + d], s2 = red_s[threadIdx.x + d];
      float m = fmaxf(m1, m2);
      float s = 0.f;
      if (m > -FLT_MAX) s = s1 * expf(m1 - m) + s2 * expf(m2 - m);
      red_m[threadIdx.x] = m; red_s[threadIdx.x] = s;
    }
    __syncthreads();
  }
  if (threadIdx.x == 0) { scal[0] = red_m[0]; scal[1] = red_s[0]; }
}

// ---------- K9: weighted segment_sum by sub (atomic-free, wave/node); unnormalized
__global__ void k_aggsum(const int* __restrict__ off, const int2* __restrict__ rec_sub,
                         const float* __restrict__ scores, const float* __restrict__ hn,
                         const float* __restrict__ scal,
                         float* __restrict__ t, float* __restrict__ wsum, int N, int E) {
  int lane = threadIdx.x & 63;
  int node = blockIdx.x * (blockDim.x >> 6) + (threadIdx.x >> 6);
  if (node >= N) return;
  float gmax = scal[0];
  int b = off[N + node] - E;
  int en = (node == N - 1) ? E : (off[N + node + 1] - E);
  float tacc = 0.f, wacc = 0.f;
  for (int base = b; base < en; base += 64) {
    int cnt = min(64, en - base);
    int objr = 0;
    float sr = 0.f;
    if (lane < cnt) { objr = rec_sub[base + lane].x; sr = scores[base + lane]; }
    for (int i = 0; i < cnt; i++) {
      int obj = __shfl(objr, i);
      float w = expf(__shfl(sr, i) - gmax);
      tacc += w * hn[(size_t)obj * 64 + lane];
      wacc += w;
    }
  }
  t[(size_t)node * 64 + lane] = tacc;
  if (lane == 0) wsum[node] = wacc;
}

// ---------- K10: out = (t @ Wnode_w + wsum * Wnode_b) / gsum
__global__ void __launch_bounds__(256, 2)
k_mm_bias(const float* __restrict__ A, const float* __restrict__ W,
          const float* __restrict__ bias, const float* __restrict__ wsum,
          const float* __restrict__ scal, float* __restrict__ C, int N) {
  int n = blockIdx.x * blockDim.x + threadIdx.x;
  if (n >= N) return;
  float inv = 1.f / scal[1];
  float a[64];
  const float4* A4 = (const float4*)(A + (size_t)n * 64);
#pragma unroll
  for (int k4 = 0; k4 < 16; k4++) {
    float4 h = A4[k4];
    a[k4 * 4 + 0] = h.x; a[k4 * 4 + 1] = h.y; a[k4 * 4 + 2] = h.z; a[k4 * 4 + 3] = h.w;
  }
  float wsn = wsum[n];
  float acc[64];
#pragma unroll
  for (int j = 0; j < 64; j++) acc[j] = wsn * bias[j];  // uniform -> s_load
#pragma unroll
  for (int k = 0; k < 64; k++) {
    float ak = a[k];
#pragma unroll
    for (int j = 0; j < 64; j++) acc[j] += ak * W[k * 64 + j];  // uniform -> s_load
  }
  float4* C4 = (float4*)(C + (size_t)n * 64);
#pragma unroll
  for (int q = 0; q < 16; q++)
    C4[q] = make_float4(acc[q * 4] * inv, acc[q * 4 + 1] * inv,
                        acc[q * 4 + 2] * inv, acc[q * 4 + 3] * inv);
}

extern "C" void kernel_launch(void* const* d_in, const int* in_sizes, int n_in,
                              void* d_out, int out_size, void* d_ws, size_t ws_size,
                              hipStream_t stream) {
  const float* hidden    = (const float*)d_in[0];
  const float* rela      = (const float*)d_in[1];
  const float* Ws        = (const float*)d_in[2];
  const float* Wr        = (const float*)d_in[3];
  const float* Wqr_w     = (const float*)d_in[4];
  const float* Wqr_b     = (const float*)d_in[5];
  const float* walpha_w  = (const float*)d_in[6];
  const float* walpha_b  = (const float*)d_in[7];
  const float* Wh        = (const float*)d_in[8];
  const float* attn_fc_w = (const float*)d_in[9];
  const float* attn_fc_b = (const float*)d_in[10];
  const float* Wnode_w   = (const float*)d_in[11];
  const float* Wnode_b   = (const float*)d_in[12];
  const int*   q_rel     = (const int*)d_in[14];
  const int*   edges     = (const int*)d_in[15];

  int N = in_sizes[0] / 64;      // 500000
  int E = in_sizes[15] / 6;      // 1000000
  int nrel = in_sizes[1] / 64;   // 401
  int batch = in_sizes[14];      // 32

  char* w = (char*)d_ws;
  size_t o = 0;
  float* aggT    = (float*)(w + o); o += (size_t)N * 64 * 4;   // agg, then t (aliased)
  float* P       = (float*)(w + o); o += (size_t)N * 5 * 4;    // later: u,v alias here
  int4*  rec_obj = (int4*)(w + o);  o += (size_t)E * 16;
  int2*  rec_sub = (int2*)(w + o);  o += (size_t)E * 8;
  int*   cnt     = (int*)(w + o);   o += (size_t)2 * N * 4;    // counts -> cursors; later scores alias
  int*   off     = (int*)(w + o);   o += (size_t)2 * N * 4;
  float* wsum    = (float*)(w + o); o += (size_t)N * 4;
  int*   part    = (int*)(w + o);   o += 1024 * 4;
  float* pmax    = (float*)(w + o); o += SOFT_G * 4;
  float* psum    = (float*)(w + o); o += SOFT_G * 4;
  float* s2t     = (float*)(w + o); o += (size_t)nrel * 5 * 4;
  float* s3t     = (float*)(w + o); o += (size_t)batch * 5 * 4;
  float* scal    = (float*)(w + o); o += 2 * 4;

  float* u = P;                 // P dead after k_scatter
  float* v = P + N;
  float* scores = (float*)cnt;  // cursors dead after k_scatter (E*4 <= 2N*4)
  float* hn = (float*)d_out;    // lives in d_out until K10 overwrites

  k_tables<<<16, 256, 0, stream>>>(rela, Wr, Wqr_w, Wqr_b, q_rel, s2t, s3t, nrel, batch);
  k_proj<<<(N + 255) / 256, 256, 0, stream>>>(hidden, Ws, P, N);
  hipMemsetAsync(cnt, 0, (size_t)2 * N * 4, stream);
  k_hist<<<(E + 255) / 256, 256, 0, stream>>>(edges, cnt, E, N);
  int SCAN_N = 2 * N;
  int nblk = (SCAN_N + SCAN_CHUNK - 1) / SCAN_CHUNK;  // 977 <= 1024
  k_scan_partial<<<nblk, SCAN_BLK, 0, stream>>>(cnt, part, SCAN_N);
  k_scan_top<<<1, 1024, 0, stream>>>(part, nblk);
  k_scan_final<<<nblk, SCAN_BLK, 0, stream>>>(cnt, part, off, SCAN_N);
  hipMemcpyAsync(cnt, off, (size_t)2 * N * 4, hipMemcpyDeviceToDevice, stream);  // cursors
  k_scatter<<<(E + 255) / 256, 256, 0, stream>>>(edges, P, s2t, s3t, walpha_w, walpha_b,
                                                 cnt, rec_obj, rec_sub, E, N);
  k_agg<<<(N + 3) / 4, 256, 0, stream>>>(off, rec_obj, hidden, rela, aggT, N);
  k_mm_uv<<<(N + 255) / 256, 256, 0, stream>>>(aggT, Wh, attn_fc_w, hn, u, v, N);
  k_scores<<<SOFT_G, 256, 0, stream>>>(rec_sub, u, v, attn_fc_b, scores, pmax, psum, E);
  k_softmax_final<<<1, 256, 0, stream>>>(pmax, psum, scal, SOFT_G);
  k_aggsum<<<(N + 3) / 4, 256, 0, stream>>>(off, rec_sub, scores, hn, scal, aggT /*t*/, wsum, N, E);
  k_mm_bias<<<(N + 255) / 256, 256, 0, stream>>>(aggT /*t*/, Wnode_w, Wnode_b, wsum, scal,
                                                 (float*)d_out, N);
}